// Round 13
// baseline (175.708 us; speedup 1.0000x reference)
//
#include <hip/hip_runtime.h>
#include <stdint.h>

#define T_SEQ 4096
#define CC    128
#define HH    32
#define QB    16               // query rows per attn wave
#define KC    32               // keys per chunk
#define BPB   (T_SEQ / QB)     // 256 row-blocks per batch
#define PST   36               // floats per row in a partial entry

typedef __attribute__((ext_vector_type(8))) short short8v;   // 8 bf16
typedef __attribute__((ext_vector_type(4))) float f32x4;

__device__ __forceinline__ unsigned short b16r(float x) {   // RNE fp32->bf16
    unsigned int u = __float_as_uint(x);
    return (unsigned short)((u + 0x7FFFu + ((u >> 16) & 1u)) >> 16);
}
__device__ __forceinline__ float b16f(unsigned short h) {
    return __uint_as_float(((unsigned int)h) << 16);
}
__device__ __forceinline__ unsigned int pk_bf16(float lo, float hi) {
    unsigned int r;
    asm("v_cvt_pk_bf16_f32 %0, %1, %2" : "=v"(r) : "v"(lo), "v"(hi));
    return r;   // low16 = bf16(lo), high16 = bf16(hi)
}

// ---------------------------------------------------------------------------
// Projection v2 (unchanged, r10-verified: dropped 95us -> below top-5).
// W staged in LDS (padded rows) + x tile in LDS. 32 rows/block.
// ---------------------------------------------------------------------------
__global__ __launch_bounds__(256) void proj_kernel(
    const float* __restrict__ x,
    const float* __restrict__ Wk,
    const float* __restrict__ Wq,
    const float* __restrict__ Wv,
    unsigned short* __restrict__ qhp, unsigned short* __restrict__ qlp,
    unsigned short* __restrict__ khp, unsigned short* __restrict__ klp,
    unsigned short* __restrict__ vth, unsigned short* __restrict__ vtl)
{
    __shared__ __align__(16) float ws[3 * 32 * 132];   // W padded: 132 f/row
    __shared__ __align__(16) float xs[32 * CC];        // x tile (broadcast-read)

    const int t = threadIdx.x;
    const long rowBase = (long)blockIdx.x * 32;

    // stage W: 3072 float4, 12 per thread, coalesced; mat uniform per i
    #pragma unroll
    for (int i = 0; i < 12; ++i) {
        const int f4  = t + i * 256;          // 0..3071
        const int mat = f4 >> 10;             // uniform per i (256 | 1024)
        const int rem = f4 & 1023;            // float4 index within mat
        const int row = rem >> 5;
        const int col = rem & 31;
        const float* src = (mat == 0) ? Wk : ((mat == 1) ? Wq : Wv);
        const float4 w = ((const float4*)src)[rem];
        *(float4*)&ws[(mat * 32 + row) * 132 + col * 4] = w;
    }
    // stage x tile: 32 rows * 128 f = 1024 float4, 4 per thread, coalesced
    #pragma unroll
    for (int i = 0; i < 4; ++i) {
        ((float4*)xs)[t + i * 256] = ((const float4*)(x + rowBase * CC))[t + i * 256];
    }
    __syncthreads();

    const int h  = t & 31;
    const int rq = t >> 5;

    const float* wkr = &ws[(0 * 32 + h) * 132];
    const float* wqr = &ws[(1 * 32 + h) * 132];
    const float* wvr = &ws[(2 * 32 + h) * 132];
    const float* xr  = &xs[rq * CC];

    float ak[4] = {0.f, 0.f, 0.f, 0.f};
    float aq[4] = {0.f, 0.f, 0.f, 0.f};
    float av[4] = {0.f, 0.f, 0.f, 0.f};

    #pragma unroll 4
    for (int c = 0; c < 32; ++c) {
        const float4 wk4 = *(const float4*)(wkr + c * 4);
        const float4 wq4 = *(const float4*)(wqr + c * 4);
        const float4 wv4 = *(const float4*)(wvr + c * 4);
        #pragma unroll
        for (int i = 0; i < 4; ++i) {
            const float4 xv = *(const float4*)(xr + i * 8 * CC + c * 4);
            ak[i] = fmaf(xv.x, wk4.x, ak[i]); ak[i] = fmaf(xv.y, wk4.y, ak[i]);
            ak[i] = fmaf(xv.z, wk4.z, ak[i]); ak[i] = fmaf(xv.w, wk4.w, ak[i]);
            aq[i] = fmaf(xv.x, wq4.x, aq[i]); aq[i] = fmaf(xv.y, wq4.y, aq[i]);
            aq[i] = fmaf(xv.z, wq4.z, aq[i]); aq[i] = fmaf(xv.w, wq4.w, aq[i]);
            av[i] = fmaf(xv.x, wv4.x, av[i]); av[i] = fmaf(xv.y, wv4.y, av[i]);
            av[i] = fmaf(xv.z, wv4.z, av[i]); av[i] = fmaf(xv.w, wv4.w, av[i]);
        }
    }

    const float qscale = 0.17677669529663687f * 1.4426950408889634f; // 1/sqrt(32)*log2(e)
    #pragma unroll
    for (int i = 0; i < 4; ++i) {
        const long row = rowBase + rq + i * 8;
        const float kv = ak[i];
        const float qv = aq[i] * qscale;
        const float vv = av[i];

        const unsigned short khi = b16r(kv);
        khp[row * HH + h] = khi;
        klp[row * HH + h] = b16r(kv - b16f(khi));
        const unsigned short qhi = b16r(qv);
        qhp[row * HH + h] = qhi;
        qlp[row * HH + h] = b16r(qv - b16f(qhi));
        const unsigned short vhi = b16r(vv);
        const int bb = (int)(row >> 12);          // /T_SEQ
        const int tt = ((int)row >> 5) & 127;     // key-tile
        const int kk = (int)row & 31;             // key-in-tile
        const long vtix = (((long)(bb * 128 + tt) * 32) + h) * 32 + kk;
        vth[vtix] = vhi;
        vtl[vtix] = b16r(vv - b16f(vhi));
    }
}

// ---------------------------------------------------------------------------
// MFMA flash attention partial, v2: 4 independent work-units per 256-thread
// block (1 per wave; no LDS, no barriers). Round-10 profile showed 30%
// occupancy at 1-wave workgroups (WG-slot cap ~16/CU) with neither pipe
// saturated -> pack 4 waves/WG so 32 waves/CU are schedulable; launch_bounds
// (256,8) pins VGPR<=64 (r10 used 44) for 8 waves/SIMD. Per-wave math and
// layout identical to the r8/r10-passed kernel; per-chunk addressing strength-
// reduced to pointer increments.
// ---------------------------------------------------------------------------
__global__ __launch_bounds__(256, 8) void attn_partial(
    const unsigned short* __restrict__ qhp, const unsigned short* __restrict__ qlp,
    const unsigned short* __restrict__ khp, const unsigned short* __restrict__ klp,
    const unsigned short* __restrict__ vth, const unsigned short* __restrict__ vtl,
    float* __restrict__ part, int segs)
{
    const int tid  = threadIdx.x & 63;            // lane within wave
    const int unit = blockIdx.x * 4 + (threadIdx.x >> 6);
    const int r16 = tid & 15;
    const int g   = tid >> 4;
    const int g8  = g * 8;

    const int nunits = gridDim.x * 4;
    const int nb  = nunits / segs;             // B * BPB
    const int seg = unit / nb;
    const int rem = unit - seg * nb;
    const int b   = rem >> 8;                  // / BPB
    const int rbi = rem & (BPB - 1);
    const int rb  = BPB - 1 - rbi;             // heavy row-blocks first
    const int qbase = rb * QB;
    const int qrow  = qbase + r16;             // batch-local

    const int nChunks = (qbase + QB + KC - 1) / KC;
    const int t0 = seg * nChunks / segs;
    const int t1 = (seg + 1) * nChunks / segs;

    float* pe = part + ((long)(b * BPB + rb) * segs + seg) * (QB * PST);

    if (t0 >= t1) {                            // empty segment
        #pragma unroll
        for (int rr = 0; rr < 4; ++rr) {
            pe[(4 * g + rr) * PST + r16]      = 0.f;
            pe[(4 * g + rr) * PST + 16 + r16] = 0.f;
        }
        if (tid < 16) { pe[r16 * PST + 32] = -1e30f; pe[r16 * PST + 33] = 0.f; }
        return;
    }

    // Q B-fragments (col = r16 = Q-row, k-dims g*8..+7), hoisted
    const long qoff = ((long)b * T_SEQ + qbase + r16) * HH + g8;
    const short8v qhf = *(const short8v*)(qhp + qoff);
    const short8v qlf = *(const short8v*)(qlp + qoff);

    const unsigned short* khb = khp + (long)b * T_SEQ * HH;
    const unsigned short* klb = klp + (long)b * T_SEQ * HH;
    const unsigned short* vthb = vth + (long)b * (T_SEQ / 32) * 1024;
    const unsigned short* vtlb = vtl + (long)b * (T_SEQ / 32) * 1024;

    // per-chunk pointers (incremented; no per-iter address rebuild)
    const unsigned short* pKh = khb + (long)t0 * KC * HH + (long)r16 * HH + g8;
    const unsigned short* pKl = klb + (long)t0 * KC * HH + (long)r16 * HH + g8;
    const unsigned short* pVh = vthb + (long)t0 * 1024 + (long)r16 * 32 + g8;
    const unsigned short* pVl = vtlb + (long)t0 * 1024 + (long)r16 * 32 + g8;
    int kq0 = qrow - t0 * KC - 4 * g;          // causal-mask counter

    float m = 0.f, lsum = 0.f;
    f32x4 o0 = {0.f, 0.f, 0.f, 0.f};
    f32x4 o1 = {0.f, 0.f, 0.f, 0.f};

    const int sA = r16 + ((g & 1) << 5);       // P-shuffle source lanes
    const int sB = sA + 16;
    const bool hiHalf = (g >= 2);
    const int g4 = g << 2;
    const float NEG = -1e30f;

    for (int c = t0; c < t1; ++c) {
        // K A-fragments (row = key = r16, k-dims g*8..+7), two 16-key tiles
        const short8v kh0 = *(const short8v*)(pKh);
        const short8v kh1 = *(const short8v*)(pKh + 16 * HH);
        const short8v kl0 = *(const short8v*)(pKl);
        const short8v kl1 = *(const short8v*)(pKl + 16 * HH);
        // V B-fragments (col = dim-in-half = r16, keys g*8..+7), two halves
        const short8v vh0 = *(const short8v*)(pVh);
        const short8v vh1 = *(const short8v*)(pVh + 512);
        const short8v vl0 = *(const short8v*)(pVl);
        const short8v vl1 = *(const short8v*)(pVl + 512);
        pKh += KC * HH; pKl += KC * HH; pVh += 1024; pVl += 1024;

        // S^T tiles, bf16x3 split: Kh*Qh + Kh*Ql + Kl*Qh
        f32x4 s0 = {0.f, 0.f, 0.f, 0.f}, s1 = {0.f, 0.f, 0.f, 0.f};
        s0 = __builtin_amdgcn_mfma_f32_16x16x32_bf16(kh0, qhf, s0, 0, 0, 0);
        s0 = __builtin_amdgcn_mfma_f32_16x16x32_bf16(kh0, qlf, s0, 0, 0, 0);
        s0 = __builtin_amdgcn_mfma_f32_16x16x32_bf16(kl0, qhf, s0, 0, 0, 0);
        s1 = __builtin_amdgcn_mfma_f32_16x16x32_bf16(kh1, qhf, s1, 0, 0, 0);
        s1 = __builtin_amdgcn_mfma_f32_16x16x32_bf16(kh1, qlf, s1, 0, 0, 0);
        s1 = __builtin_amdgcn_mfma_f32_16x16x32_bf16(kl1, qhf, s1, 0, 0, 0);

        // causal mask: key (ck + 4g + reg [+16]) > qrow  ->  -inf
        const int kq1 = kq0 - 16;
        s0[0] = (0 > kq0) ? NEG : s0[0];
        s0[1] = (1 > kq0) ? NEG : s0[1];
        s0[2] = (2 > kq0) ? NEG : s0[2];
        s0[3] = (3 > kq0) ? NEG : s0[3];
        s1[0] = (0 > kq1) ? NEG : s1[0];
        s1[1] = (1 > kq1) ? NEG : s1[1];
        s1[2] = (2 > kq1) ? NEG : s1[2];
        s1[3] = (3 > kq1) ? NEG : s1[3];
        kq0 -= KC;

        // tile max across the row's 4 lane-groups
        float tmax = fmaxf(fmaxf(fmaxf(s0[0], s0[1]), fmaxf(s0[2], s0[3])),
                           fmaxf(fmaxf(s1[0], s1[1]), fmaxf(s1[2], s1[3])));
        tmax = fmaxf(tmax, __shfl_xor(tmax, 16));
        tmax = fmaxf(tmax, __shfl_xor(tmax, 32));

        // p = exp2(s - m_old) (deferred rescale)
        const float p00 = __builtin_amdgcn_exp2f(s0[0] - m);
        const float p01 = __builtin_amdgcn_exp2f(s0[1] - m);
        const float p02 = __builtin_amdgcn_exp2f(s0[2] - m);
        const float p03 = __builtin_amdgcn_exp2f(s0[3] - m);
        const float p10 = __builtin_amdgcn_exp2f(s1[0] - m);
        const float p11 = __builtin_amdgcn_exp2f(s1[1] - m);
        const float p12 = __builtin_amdgcn_exp2f(s1[2] - m);
        const float p13 = __builtin_amdgcn_exp2f(s1[3] - m);
        float ps = ((p00 + p01) + (p02 + p03)) + ((p10 + p11) + (p12 + p13));
        ps += __shfl_xor(ps, 16);
        ps += __shfl_xor(ps, 32);

        // split P into bf16 hi/lo word pairs (word = 2 consecutive regs)
        const unsigned int h0a = pk_bf16(p00, p01), h0b = pk_bf16(p02, p03);
        const unsigned int h1a = pk_bf16(p10, p11), h1b = pk_bf16(p12, p13);
        const unsigned int l0a = pk_bf16(p00 - b16f((unsigned short)h0a),
                                         p01 - b16f((unsigned short)(h0a >> 16)));
        const unsigned int l0b = pk_bf16(p02 - b16f((unsigned short)h0b),
                                         p03 - b16f((unsigned short)(h0b >> 16)));
        const unsigned int l1a = pk_bf16(p10 - b16f((unsigned short)h1a),
                                         p11 - b16f((unsigned short)(h1a >> 16)));
        const unsigned int l1b = pk_bf16(p12 - b16f((unsigned short)h1b),
                                         p13 - b16f((unsigned short)(h1b >> 16)));

        // shuffle P words into PV A-fragment layout (keys 8g+2jw.. per word)
        unsigned int xa, xb;
        xa = __shfl(h0a, sA); xb = __shfl(h1a, sA);
        const unsigned int H0 = hiHalf ? xb : xa;
        xa = __shfl(h0b, sA); xb = __shfl(h1b, sA);
        const unsigned int H1 = hiHalf ? xb : xa;
        xa = __shfl(h0a, sB); xb = __shfl(h1a, sB);
        const unsigned int H2 = hiHalf ? xb : xa;
        xa = __shfl(h0b, sB); xb = __shfl(h1b, sB);
        const unsigned int H3 = hiHalf ? xb : xa;
        xa = __shfl(l0a, sA); xb = __shfl(l1a, sA);
        const unsigned int L0 = hiHalf ? xb : xa;
        xa = __shfl(l0b, sA); xb = __shfl(l1b, sA);
        const unsigned int L1 = hiHalf ? xb : xa;
        xa = __shfl(l0a, sB); xb = __shfl(l1a, sB);
        const unsigned int L2 = hiHalf ? xb : xa;
        xa = __shfl(l0b, sB); xb = __shfl(l1b, sB);
        const unsigned int L3 = hiHalf ? xb : xa;

        uint4 hw; hw.x = H0; hw.y = H1; hw.z = H2; hw.w = H3;
        uint4 lw; lw.x = L0; lw.y = L1; lw.z = L2; lw.w = L3;
        const short8v pH = __builtin_bit_cast(short8v, hw);
        const short8v pL = __builtin_bit_cast(short8v, lw);

        // PV, bf16x3 split: Ph*Vh + Ph*Vl + Pl*Vh (accumulate fp32)
        o0 = __builtin_amdgcn_mfma_f32_16x16x32_bf16(pH, vh0, o0, 0, 0, 0);
        o0 = __builtin_amdgcn_mfma_f32_16x16x32_bf16(pH, vl0, o0, 0, 0, 0);
        o0 = __builtin_amdgcn_mfma_f32_16x16x32_bf16(pL, vh0, o0, 0, 0, 0);
        o1 = __builtin_amdgcn_mfma_f32_16x16x32_bf16(pH, vh1, o1, 0, 0, 0);
        o1 = __builtin_amdgcn_mfma_f32_16x16x32_bf16(pH, vl1, o1, 0, 0, 0);
        o1 = __builtin_amdgcn_mfma_f32_16x16x32_bf16(pL, vh1, o1, 0, 0, 0);

        // deferred rescale (O-lane rows are 4g+r -> pull per-row corr)
        const float mn   = fmaxf(m, tmax);
        const float corr = __builtin_amdgcn_exp2f(m - mn);
        lsum = (lsum + ps) * corr;
        m = mn;
        const float c0 = __shfl(corr, g4);
        const float c1 = __shfl(corr, g4 + 1);
        const float c2 = __shfl(corr, g4 + 2);
        const float c3 = __shfl(corr, g4 + 3);
        o0[0] *= c0; o0[1] *= c1; o0[2] *= c2; o0[3] *= c3;
        o1[0] *= c0; o1[1] *= c1; o1[2] *= c2; o1[3] *= c3;
    }

    // write partials: O-lane holds rows 4g+r, dim halves r16 / 16+r16
    pe[(4 * g + 0) * PST + r16] = o0[0];
    pe[(4 * g + 1) * PST + r16] = o0[1];
    pe[(4 * g + 2) * PST + r16] = o0[2];
    pe[(4 * g + 3) * PST + r16] = o0[3];
    pe[(4 * g + 0) * PST + 16 + r16] = o1[0];
    pe[(4 * g + 1) * PST + 16 + r16] = o1[1];
    pe[(4 * g + 2) * PST + 16 + r16] = o1[2];
    pe[(4 * g + 3) * PST + 16 + r16] = o1[3];
    if (tid < 16) { pe[r16 * PST + 32] = m; pe[r16 * PST + 33] = lsum; }
}

// ---------------------------------------------------------------------------
// Merge split-K partials: out = sum_s w_s*acc_s / sum_s w_s*l_s, w_s=2^(m_s-M)
// ---------------------------------------------------------------------------
__global__ __launch_bounds__(256) void merge_kernel(
    const float* __restrict__ part,
    float* __restrict__ out,
    int segs)
{
    const int gid = blockIdx.x * 256 + threadIdx.x;   // B*T*4 threads
    const int row = gid >> 2;
    const int sub = gid & 3;
    const int b   = row / T_SEQ;
    const int tr  = row - b * T_SEQ;
    const int rb  = tr >> 4;                   // / QB
    const int r   = tr & (QB - 1);

    const float* pe = part + ((long)(b * BPB + rb) * segs) * (QB * PST) + r * PST;
    const long stride = QB * PST;

    float M = -1e30f;
    for (int s = 0; s < segs; ++s) M = fmaxf(M, pe[s * stride + 32]);

    float L = 0.f;
    float a[8];
    #pragma unroll
    for (int d = 0; d < 8; ++d) a[d] = 0.f;

    for (int s = 0; s < segs; ++s) {
        const float* p = pe + s * stride;
        const float w = __builtin_amdgcn_exp2f(p[32] - M);
        L = fmaf(w, p[33], L);
        const float4 a0 = *(const float4*)(p + sub * 8);
        const float4 a1 = *(const float4*)(p + sub * 8 + 4);
        a[0] = fmaf(w, a0.x, a[0]); a[1] = fmaf(w, a0.y, a[1]);
        a[2] = fmaf(w, a0.z, a[2]); a[3] = fmaf(w, a0.w, a[3]);
        a[4] = fmaf(w, a1.x, a[4]); a[5] = fmaf(w, a1.y, a[5]);
        a[6] = fmaf(w, a1.z, a[6]); a[7] = fmaf(w, a1.w, a[7]);
    }

    const float inv = 1.0f / L;
    float4 o0, o1;
    o0.x = a[0] * inv; o0.y = a[1] * inv; o0.z = a[2] * inv; o0.w = a[3] * inv;
    o1.x = a[4] * inv; o1.y = a[5] * inv; o1.z = a[6] * inv; o1.w = a[7] * inv;
    float* op = out + (long)row * HH + sub * 8;
    *(float4*)op       = o0;
    *(float4*)(op + 4) = o1;
}

// ---------------------------------------------------------------------------
extern "C" void kernel_launch(void* const* d_in, const int* in_sizes, int n_in,
                              void* d_out, int out_size, void* d_ws, size_t ws_size,
                              hipStream_t stream)
{
    const float* x  = (const float*)d_in[0];
    const float* Wk = (const float*)d_in[1];
    const float* Wq = (const float*)d_in[2];
    const float* Wv = (const float*)d_in[3];

    const int  B  = in_sizes[0] / (T_SEQ * CC);   // 4
    const long NT = (long)B * T_SEQ;              // 16384 rows

    unsigned short* qhp = (unsigned short*)d_ws;  // each array: NT*32 bf16
    unsigned short* qlp = qhp + NT * HH;
    unsigned short* khp = qlp + NT * HH;
    unsigned short* klp = khp + NT * HH;
    unsigned short* vth = klp + NT * HH;          // transposed tiles
    unsigned short* vtl = vth + NT * HH;
    float* partbuf = (float*)(vtl + NT * HH);
    float* out = (float*)d_out;

    const size_t baseBytes = (size_t)6 * NT * HH * sizeof(unsigned short);
    int segs = 8;
    while (segs > 1 &&
           baseBytes + (size_t)B * BPB * segs * QB * PST * sizeof(float) > ws_size)
        segs >>= 1;

    proj_kernel<<<dim3((int)(NT / 32)), dim3(256), 0, stream>>>(
        x, Wk, Wq, Wv, qhp, qlp, khp, klp, vth, vtl);

    // 4 work-units per 256-thread block (1 per wave)
    attn_partial<<<dim3(B * BPB * segs / 4), dim3(256), 0, stream>>>(
        qhp, qlp, khp, klp, vth, vtl, partbuf, segs);

    merge_kernel<<<dim3((int)(NT * 4 / 256)), dim3(256), 0, stream>>>(
        partbuf, out, segs);
}

// Round 14
// 133.592 us; speedup vs baseline: 1.3153x; 1.3153x over previous
//
#include <hip/hip_runtime.h>
#include <stdint.h>

#define T_SEQ 4096
#define CC    128
#define HH    32
#define QB    16               // query rows per attn wave
#define KC    32               // keys per chunk
#define BPB   (T_SEQ / QB)     // 256 row-blocks per batch
#define PST   36               // floats per row in a partial entry

typedef __attribute__((ext_vector_type(8))) short short8v;   // 8 bf16
typedef __attribute__((ext_vector_type(4))) float f32x4;

__device__ __forceinline__ unsigned short b16r(float x) {   // RNE fp32->bf16
    unsigned int u = __float_as_uint(x);
    return (unsigned short)((u + 0x7FFFu + ((u >> 16) & 1u)) >> 16);
}
__device__ __forceinline__ float b16f(unsigned short h) {
    return __uint_as_float(((unsigned int)h) << 16);
}
__device__ __forceinline__ unsigned int pk_bf16(float lo, float hi) {
    unsigned int r;
    asm("v_cvt_pk_bf16_f32 %0, %1, %2" : "=v"(r) : "v"(lo), "v"(hi));
    return r;   // low16 = bf16(lo), high16 = bf16(hi)
}

// ---------------------------------------------------------------------------
// Projection v2 (unchanged, r10-verified: dropped 95us -> below top-5).
// W staged in LDS (padded rows) + x tile in LDS. 32 rows/block.
// ---------------------------------------------------------------------------
__global__ __launch_bounds__(256) void proj_kernel(
    const float* __restrict__ x,
    const float* __restrict__ Wk,
    const float* __restrict__ Wq,
    const float* __restrict__ Wv,
    unsigned short* __restrict__ qhp, unsigned short* __restrict__ qlp,
    unsigned short* __restrict__ khp, unsigned short* __restrict__ klp,
    unsigned short* __restrict__ vth, unsigned short* __restrict__ vtl)
{
    __shared__ __align__(16) float ws[3 * 32 * 132];   // W padded: 132 f/row
    __shared__ __align__(16) float xs[32 * CC];        // x tile (broadcast-read)

    const int t = threadIdx.x;
    const long rowBase = (long)blockIdx.x * 32;

    // stage W: 3072 float4, 12 per thread, coalesced; mat uniform per i
    #pragma unroll
    for (int i = 0; i < 12; ++i) {
        const int f4  = t + i * 256;          // 0..3071
        const int mat = f4 >> 10;             // uniform per i (256 | 1024)
        const int rem = f4 & 1023;            // float4 index within mat
        const int row = rem >> 5;
        const int col = rem & 31;
        const float* src = (mat == 0) ? Wk : ((mat == 1) ? Wq : Wv);
        const float4 w = ((const float4*)src)[rem];
        *(float4*)&ws[(mat * 32 + row) * 132 + col * 4] = w;
    }
    // stage x tile: 32 rows * 128 f = 1024 float4, 4 per thread, coalesced
    #pragma unroll
    for (int i = 0; i < 4; ++i) {
        ((float4*)xs)[t + i * 256] = ((const float4*)(x + rowBase * CC))[t + i * 256];
    }
    __syncthreads();

    const int h  = t & 31;
    const int rq = t >> 5;

    const float* wkr = &ws[(0 * 32 + h) * 132];
    const float* wqr = &ws[(1 * 32 + h) * 132];
    const float* wvr = &ws[(2 * 32 + h) * 132];
    const float* xr  = &xs[rq * CC];

    float ak[4] = {0.f, 0.f, 0.f, 0.f};
    float aq[4] = {0.f, 0.f, 0.f, 0.f};
    float av[4] = {0.f, 0.f, 0.f, 0.f};

    #pragma unroll 4
    for (int c = 0; c < 32; ++c) {
        const float4 wk4 = *(const float4*)(wkr + c * 4);
        const float4 wq4 = *(const float4*)(wqr + c * 4);
        const float4 wv4 = *(const float4*)(wvr + c * 4);
        #pragma unroll
        for (int i = 0; i < 4; ++i) {
            const float4 xv = *(const float4*)(xr + i * 8 * CC + c * 4);
            ak[i] = fmaf(xv.x, wk4.x, ak[i]); ak[i] = fmaf(xv.y, wk4.y, ak[i]);
            ak[i] = fmaf(xv.z, wk4.z, ak[i]); ak[i] = fmaf(xv.w, wk4.w, ak[i]);
            aq[i] = fmaf(xv.x, wq4.x, aq[i]); aq[i] = fmaf(xv.y, wq4.y, aq[i]);
            aq[i] = fmaf(xv.z, wq4.z, aq[i]); aq[i] = fmaf(xv.w, wq4.w, aq[i]);
            av[i] = fmaf(xv.x, wv4.x, av[i]); av[i] = fmaf(xv.y, wv4.y, av[i]);
            av[i] = fmaf(xv.z, wv4.z, av[i]); av[i] = fmaf(xv.w, wv4.w, av[i]);
        }
    }

    const float qscale = 0.17677669529663687f * 1.4426950408889634f; // 1/sqrt(32)*log2(e)
    #pragma unroll
    for (int i = 0; i < 4; ++i) {
        const long row = rowBase + rq + i * 8;
        const float kv = ak[i];
        const float qv = aq[i] * qscale;
        const float vv = av[i];

        const unsigned short khi = b16r(kv);
        khp[row * HH + h] = khi;
        klp[row * HH + h] = b16r(kv - b16f(khi));
        const unsigned short qhi = b16r(qv);
        qhp[row * HH + h] = qhi;
        qlp[row * HH + h] = b16r(qv - b16f(qhi));
        const unsigned short vhi = b16r(vv);
        const int bb = (int)(row >> 12);          // /T_SEQ
        const int tt = ((int)row >> 5) & 127;     // key-tile
        const int kk = (int)row & 31;             // key-in-tile
        const long vtix = (((long)(bb * 128 + tt) * 32) + h) * 32 + kk;
        vth[vtix] = vhi;
        vtl[vtix] = b16r(vv - b16f(vhi));
    }
}

// ---------------------------------------------------------------------------
// MFMA flash attention partial, v3: 4 independent work-units per 256-thread
// block (1 per wave; no LDS, no barriers). r13 lesson: (256,8) forced the
// unified VGPR/AGPR budget to 32 -> scratch spill (FETCH 20->54MB, WRITE
// 18->44MB, VALUBusy 15%). Occupancy DID rise 30->45% (packing works), so
// keep packing but relax to (256,4): VGPR cap 128, compiler emits the r10
// 44-VGPR no-spill code; HW can still co-schedule 8 waves/SIMD naturally.
// ---------------------------------------------------------------------------
__global__ __launch_bounds__(256, 4) void attn_partial(
    const unsigned short* __restrict__ qhp, const unsigned short* __restrict__ qlp,
    const unsigned short* __restrict__ khp, const unsigned short* __restrict__ klp,
    const unsigned short* __restrict__ vth, const unsigned short* __restrict__ vtl,
    float* __restrict__ part, int segs)
{
    const int tid  = threadIdx.x & 63;            // lane within wave
    const int unit = blockIdx.x * 4 + (threadIdx.x >> 6);
    const int r16 = tid & 15;
    const int g   = tid >> 4;
    const int g8  = g * 8;

    const int nunits = gridDim.x * 4;
    const int nb  = nunits / segs;             // B * BPB
    const int seg = unit / nb;
    const int rem = unit - seg * nb;
    const int b   = rem >> 8;                  // / BPB
    const int rbi = rem & (BPB - 1);
    const int rb  = BPB - 1 - rbi;             // heavy row-blocks first
    const int qbase = rb * QB;
    const int qrow  = qbase + r16;             // batch-local

    const int nChunks = (qbase + QB + KC - 1) / KC;
    const int t0 = seg * nChunks / segs;
    const int t1 = (seg + 1) * nChunks / segs;

    float* pe = part + ((long)(b * BPB + rb) * segs + seg) * (QB * PST);

    if (t0 >= t1) {                            // empty segment
        #pragma unroll
        for (int rr = 0; rr < 4; ++rr) {
            pe[(4 * g + rr) * PST + r16]      = 0.f;
            pe[(4 * g + rr) * PST + 16 + r16] = 0.f;
        }
        if (tid < 16) { pe[r16 * PST + 32] = -1e30f; pe[r16 * PST + 33] = 0.f; }
        return;
    }

    // Q B-fragments (col = r16 = Q-row, k-dims g*8..+7), hoisted
    const long qoff = ((long)b * T_SEQ + qbase + r16) * HH + g8;
    const short8v qhf = *(const short8v*)(qhp + qoff);
    const short8v qlf = *(const short8v*)(qlp + qoff);

    const unsigned short* khb = khp + (long)b * T_SEQ * HH;
    const unsigned short* klb = klp + (long)b * T_SEQ * HH;
    const unsigned short* vthb = vth + (long)b * (T_SEQ / 32) * 1024;
    const unsigned short* vtlb = vtl + (long)b * (T_SEQ / 32) * 1024;

    // per-chunk pointers (incremented; no per-iter address rebuild)
    const unsigned short* pKh = khb + (long)t0 * KC * HH + (long)r16 * HH + g8;
    const unsigned short* pKl = klb + (long)t0 * KC * HH + (long)r16 * HH + g8;
    const unsigned short* pVh = vthb + (long)t0 * 1024 + (long)r16 * 32 + g8;
    const unsigned short* pVl = vtlb + (long)t0 * 1024 + (long)r16 * 32 + g8;
    int kq0 = qrow - t0 * KC - 4 * g;          // causal-mask counter

    float m = 0.f, lsum = 0.f;
    f32x4 o0 = {0.f, 0.f, 0.f, 0.f};
    f32x4 o1 = {0.f, 0.f, 0.f, 0.f};

    const int sA = r16 + ((g & 1) << 5);       // P-shuffle source lanes
    const int sB = sA + 16;
    const bool hiHalf = (g >= 2);
    const int g4 = g << 2;
    const float NEG = -1e30f;

    for (int c = t0; c < t1; ++c) {
        // K A-fragments (row = key = r16, k-dims g*8..+7), two 16-key tiles
        const short8v kh0 = *(const short8v*)(pKh);
        const short8v kh1 = *(const short8v*)(pKh + 16 * HH);
        const short8v kl0 = *(const short8v*)(pKl);
        const short8v kl1 = *(const short8v*)(pKl + 16 * HH);
        // V B-fragments (col = dim-in-half = r16, keys g*8..+7), two halves
        const short8v vh0 = *(const short8v*)(pVh);
        const short8v vh1 = *(const short8v*)(pVh + 512);
        const short8v vl0 = *(const short8v*)(pVl);
        const short8v vl1 = *(const short8v*)(pVl + 512);
        pKh += KC * HH; pKl += KC * HH; pVh += 1024; pVl += 1024;

        // S^T tiles, bf16x3 split: Kh*Qh + Kh*Ql + Kl*Qh
        f32x4 s0 = {0.f, 0.f, 0.f, 0.f}, s1 = {0.f, 0.f, 0.f, 0.f};
        s0 = __builtin_amdgcn_mfma_f32_16x16x32_bf16(kh0, qhf, s0, 0, 0, 0);
        s0 = __builtin_amdgcn_mfma_f32_16x16x32_bf16(kh0, qlf, s0, 0, 0, 0);
        s0 = __builtin_amdgcn_mfma_f32_16x16x32_bf16(kl0, qhf, s0, 0, 0, 0);
        s1 = __builtin_amdgcn_mfma_f32_16x16x32_bf16(kh1, qhf, s1, 0, 0, 0);
        s1 = __builtin_amdgcn_mfma_f32_16x16x32_bf16(kh1, qlf, s1, 0, 0, 0);
        s1 = __builtin_amdgcn_mfma_f32_16x16x32_bf16(kl1, qhf, s1, 0, 0, 0);

        // causal mask: key (ck + 4g + reg [+16]) > qrow  ->  -inf
        const int kq1 = kq0 - 16;
        s0[0] = (0 > kq0) ? NEG : s0[0];
        s0[1] = (1 > kq0) ? NEG : s0[1];
        s0[2] = (2 > kq0) ? NEG : s0[2];
        s0[3] = (3 > kq0) ? NEG : s0[3];
        s1[0] = (0 > kq1) ? NEG : s1[0];
        s1[1] = (1 > kq1) ? NEG : s1[1];
        s1[2] = (2 > kq1) ? NEG : s1[2];
        s1[3] = (3 > kq1) ? NEG : s1[3];
        kq0 -= KC;

        // tile max across the row's 4 lane-groups
        float tmax = fmaxf(fmaxf(fmaxf(s0[0], s0[1]), fmaxf(s0[2], s0[3])),
                           fmaxf(fmaxf(s1[0], s1[1]), fmaxf(s1[2], s1[3])));
        tmax = fmaxf(tmax, __shfl_xor(tmax, 16));
        tmax = fmaxf(tmax, __shfl_xor(tmax, 32));

        // p = exp2(s - m_old) (deferred rescale)
        const float p00 = __builtin_amdgcn_exp2f(s0[0] - m);
        const float p01 = __builtin_amdgcn_exp2f(s0[1] - m);
        const float p02 = __builtin_amdgcn_exp2f(s0[2] - m);
        const float p03 = __builtin_amdgcn_exp2f(s0[3] - m);
        const float p10 = __builtin_amdgcn_exp2f(s1[0] - m);
        const float p11 = __builtin_amdgcn_exp2f(s1[1] - m);
        const float p12 = __builtin_amdgcn_exp2f(s1[2] - m);
        const float p13 = __builtin_amdgcn_exp2f(s1[3] - m);
        float ps = ((p00 + p01) + (p02 + p03)) + ((p10 + p11) + (p12 + p13));
        ps += __shfl_xor(ps, 16);
        ps += __shfl_xor(ps, 32);

        // split P into bf16 hi/lo word pairs (word = 2 consecutive regs)
        const unsigned int h0a = pk_bf16(p00, p01), h0b = pk_bf16(p02, p03);
        const unsigned int h1a = pk_bf16(p10, p11), h1b = pk_bf16(p12, p13);
        const unsigned int l0a = pk_bf16(p00 - b16f((unsigned short)h0a),
                                         p01 - b16f((unsigned short)(h0a >> 16)));
        const unsigned int l0b = pk_bf16(p02 - b16f((unsigned short)h0b),
                                         p03 - b16f((unsigned short)(h0b >> 16)));
        const unsigned int l1a = pk_bf16(p10 - b16f((unsigned short)h1a),
                                         p11 - b16f((unsigned short)(h1a >> 16)));
        const unsigned int l1b = pk_bf16(p12 - b16f((unsigned short)h1b),
                                         p13 - b16f((unsigned short)(h1b >> 16)));

        // shuffle P words into PV A-fragment layout (keys 8g+2jw.. per word)
        unsigned int xa, xb;
        xa = __shfl(h0a, sA); xb = __shfl(h1a, sA);
        const unsigned int H0 = hiHalf ? xb : xa;
        xa = __shfl(h0b, sA); xb = __shfl(h1b, sA);
        const unsigned int H1 = hiHalf ? xb : xa;
        xa = __shfl(h0a, sB); xb = __shfl(h1a, sB);
        const unsigned int H2 = hiHalf ? xb : xa;
        xa = __shfl(h0b, sB); xb = __shfl(h1b, sB);
        const unsigned int H3 = hiHalf ? xb : xa;
        xa = __shfl(l0a, sA); xb = __shfl(l1a, sA);
        const unsigned int L0 = hiHalf ? xb : xa;
        xa = __shfl(l0b, sA); xb = __shfl(l1b, sA);
        const unsigned int L1 = hiHalf ? xb : xa;
        xa = __shfl(l0a, sB); xb = __shfl(l1a, sB);
        const unsigned int L2 = hiHalf ? xb : xa;
        xa = __shfl(l0b, sB); xb = __shfl(l1b, sB);
        const unsigned int L3 = hiHalf ? xb : xa;

        uint4 hw; hw.x = H0; hw.y = H1; hw.z = H2; hw.w = H3;
        uint4 lw; lw.x = L0; lw.y = L1; lw.z = L2; lw.w = L3;
        const short8v pH = __builtin_bit_cast(short8v, hw);
        const short8v pL = __builtin_bit_cast(short8v, lw);

        // PV, bf16x3 split: Ph*Vh + Ph*Vl + Pl*Vh (accumulate fp32)
        o0 = __builtin_amdgcn_mfma_f32_16x16x32_bf16(pH, vh0, o0, 0, 0, 0);
        o0 = __builtin_amdgcn_mfma_f32_16x16x32_bf16(pH, vl0, o0, 0, 0, 0);
        o0 = __builtin_amdgcn_mfma_f32_16x16x32_bf16(pL, vh0, o0, 0, 0, 0);
        o1 = __builtin_amdgcn_mfma_f32_16x16x32_bf16(pH, vh1, o1, 0, 0, 0);
        o1 = __builtin_amdgcn_mfma_f32_16x16x32_bf16(pH, vl1, o1, 0, 0, 0);
        o1 = __builtin_amdgcn_mfma_f32_16x16x32_bf16(pL, vh1, o1, 0, 0, 0);

        // deferred rescale (O-lane rows are 4g+r -> pull per-row corr)
        const float mn   = fmaxf(m, tmax);
        const float corr = __builtin_amdgcn_exp2f(m - mn);
        lsum = (lsum + ps) * corr;
        m = mn;
        const float c0 = __shfl(corr, g4);
        const float c1 = __shfl(corr, g4 + 1);
        const float c2 = __shfl(corr, g4 + 2);
        const float c3 = __shfl(corr, g4 + 3);
        o0[0] *= c0; o0[1] *= c1; o0[2] *= c2; o0[3] *= c3;
        o1[0] *= c0; o1[1] *= c1; o1[2] *= c2; o1[3] *= c3;
    }

    // write partials: O-lane holds rows 4g+r, dim halves r16 / 16+r16
    pe[(4 * g + 0) * PST + r16] = o0[0];
    pe[(4 * g + 1) * PST + r16] = o0[1];
    pe[(4 * g + 2) * PST + r16] = o0[2];
    pe[(4 * g + 3) * PST + r16] = o0[3];
    pe[(4 * g + 0) * PST + 16 + r16] = o1[0];
    pe[(4 * g + 1) * PST + 16 + r16] = o1[1];
    pe[(4 * g + 2) * PST + 16 + r16] = o1[2];
    pe[(4 * g + 3) * PST + 16 + r16] = o1[3];
    if (tid < 16) { pe[r16 * PST + 32] = m; pe[r16 * PST + 33] = lsum; }
}

// ---------------------------------------------------------------------------
// Merge split-K partials: out = sum_s w_s*acc_s / sum_s w_s*l_s, w_s=2^(m_s-M)
// ---------------------------------------------------------------------------
__global__ __launch_bounds__(256) void merge_kernel(
    const float* __restrict__ part,
    float* __restrict__ out,
    int segs)
{
    const int gid = blockIdx.x * 256 + threadIdx.x;   // B*T*4 threads
    const int row = gid >> 2;
    const int sub = gid & 3;
    const int b   = row / T_SEQ;
    const int tr  = row - b * T_SEQ;
    const int rb  = tr >> 4;                   // / QB
    const int r   = tr & (QB - 1);

    const float* pe = part + ((long)(b * BPB + rb) * segs) * (QB * PST) + r * PST;
    const long stride = QB * PST;

    float M = -1e30f;
    for (int s = 0; s < segs; ++s) M = fmaxf(M, pe[s * stride + 32]);

    float L = 0.f;
    float a[8];
    #pragma unroll
    for (int d = 0; d < 8; ++d) a[d] = 0.f;

    for (int s = 0; s < segs; ++s) {
        const float* p = pe + s * stride;
        const float w = __builtin_amdgcn_exp2f(p[32] - M);
        L = fmaf(w, p[33], L);
        const float4 a0 = *(const float4*)(p + sub * 8);
        const float4 a1 = *(const float4*)(p + sub * 8 + 4);
        a[0] = fmaf(w, a0.x, a[0]); a[1] = fmaf(w, a0.y, a[1]);
        a[2] = fmaf(w, a0.z, a[2]); a[3] = fmaf(w, a0.w, a[3]);
        a[4] = fmaf(w, a1.x, a[4]); a[5] = fmaf(w, a1.y, a[5]);
        a[6] = fmaf(w, a1.z, a[6]); a[7] = fmaf(w, a1.w, a[7]);
    }

    const float inv = 1.0f / L;
    float4 o0, o1;
    o0.x = a[0] * inv; o0.y = a[1] * inv; o0.z = a[2] * inv; o0.w = a[3] * inv;
    o1.x = a[4] * inv; o1.y = a[5] * inv; o1.z = a[6] * inv; o1.w = a[7] * inv;
    float* op = out + (long)row * HH + sub * 8;
    *(float4*)op       = o0;
    *(float4*)(op + 4) = o1;
}

// ---------------------------------------------------------------------------
extern "C" void kernel_launch(void* const* d_in, const int* in_sizes, int n_in,
                              void* d_out, int out_size, void* d_ws, size_t ws_size,
                              hipStream_t stream)
{
    const float* x  = (const float*)d_in[0];
    const float* Wk = (const float*)d_in[1];
    const float* Wq = (const float*)d_in[2];
    const float* Wv = (const float*)d_in[3];

    const int  B  = in_sizes[0] / (T_SEQ * CC);   // 4
    const long NT = (long)B * T_SEQ;              // 16384 rows

    unsigned short* qhp = (unsigned short*)d_ws;  // each array: NT*32 bf16
    unsigned short* qlp = qhp + NT * HH;
    unsigned short* khp = qlp + NT * HH;
    unsigned short* klp = khp + NT * HH;
    unsigned short* vth = klp + NT * HH;          // transposed tiles
    unsigned short* vtl = vth + NT * HH;
    float* partbuf = (float*)(vtl + NT * HH);
    float* out = (float*)d_out;

    const size_t baseBytes = (size_t)6 * NT * HH * sizeof(unsigned short);
    int segs = 8;
    while (segs > 1 &&
           baseBytes + (size_t)B * BPB * segs * QB * PST * sizeof(float) > ws_size)
        segs >>= 1;

    proj_kernel<<<dim3((int)(NT / 32)), dim3(256), 0, stream>>>(
        x, Wk, Wq, Wv, qhp, qlp, khp, klp, vth, vtl);

    // 4 work-units per 256-thread block (1 per wave)
    attn_partial<<<dim3(B * BPB * segs / 4), dim3(256), 0, stream>>>(
        qhp, qlp, khp, klp, vth, vtl, partbuf, segs);

    merge_kernel<<<dim3((int)(NT * 4 / 256)), dim3(256), 0, stream>>>(
        partbuf, out, segs);
}